// Round 1
// baseline (478.324 us; speedup 1.0000x reference)
//
#include <hip/hip_runtime.h>
#include <cstdint>
#include <cstddef>

// Problem constants (reference: B=256, T=256, D=512, H=8, hd=64)
#define B_   256
#define T_   256
#define D_   512
#define H_   8
#define HD_  64
#define BT_  65536
#define KDIM 512

typedef __bf16 bf16x8_t __attribute__((ext_vector_type(8)));
typedef __bf16 bf16x4_t __attribute__((ext_vector_type(4)));
typedef float  f32x4_t  __attribute__((ext_vector_type(4)));

__device__ __forceinline__ void gload16(const void* gp, void* lp) {
  // async global->LDS, 16B per lane; LDS dest = wave-uniform base + lane*16
  __builtin_amdgcn_global_load_lds(
      (const __attribute__((address_space(1))) void*)gp,
      (__attribute__((address_space(3))) void*)lp, 16, 0, 0);
}

// ---------------- prep kernels ----------------

__global__ __launch_bounds__(256) void cast_weights(
    const float* __restrict__ wq, const float* __restrict__ wk,
    const float* __restrict__ wv, const float* __restrict__ wo,
    __bf16* __restrict__ wb) {
  for (int i = blockIdx.x * 256 + threadIdx.x; i < 262144; i += gridDim.x * 256) {
    int which = i >> 16;            // 65536 float4 per 512x512 weight
    int off   = (i & 65535) * 4;
    const float* src = (which == 0) ? wq : (which == 1) ? wk : (which == 2) ? wv : wo;
    f32x4_t v = *(const f32x4_t*)&src[off];
    bf16x4_t o;
    o[0] = (__bf16)v[0]; o[1] = (__bf16)v[1]; o[2] = (__bf16)v[2]; o[3] = (__bf16)v[3];
    *(bf16x4_t*)&wb[(size_t)which * 262144 + off] = o;
  }
}

__global__ __launch_bounds__(256) void rope_init(float* __restrict__ rc,
                                                 float* __restrict__ rs) {
  int idx = blockIdx.x * 256 + threadIdx.x;
  if (idx < T_ * 32) {
    int t = idx >> 5, j = idx & 31;
    float inv = powf(10000.f, -(float)j * (1.0f / 32.0f));  // 10000^(-2j/64)
    float a = (float)t * inv;
    rc[idx] = cosf(a);
    rs[idx] = sinf(a);
  }
}

__global__ __launch_bounds__(256) void cast_x(const float* __restrict__ x,
                                              __bf16* __restrict__ xb) {
  for (size_t i = blockIdx.x * 256 + threadIdx.x; i < (size_t)BT_ * D_ / 4;
       i += (size_t)gridDim.x * 256) {
    f32x4_t v = *(const f32x4_t*)&x[i * 4];
    bf16x4_t o;
    o[0] = (__bf16)v[0]; o[1] = (__bf16)v[1]; o[2] = (__bf16)v[2]; o[3] = (__bf16)v[3];
    *(bf16x4_t*)&xb[i * 4] = o;
  }
}

// ---------------- bt-GEMM: out[m,e] = sum_d A[m,d] * W[e,d] ----------------
// 128x128 tile, BK=32, 4 waves (2x2), m97 structure.
// MODE 0: write bf16 scattered to (B,H,T,hd) qkv layout, blockIdx.z selects weight/out.
// MODE 1: write f32 row-major (m, 512) to d_out.
template <int MODE>
__global__ __launch_bounds__(256) void gemm_bt(const __bf16* __restrict__ A,
                                               const __bf16* __restrict__ W,
                                               void* __restrict__ outp) {
  __shared__ __bf16 Al[128 * 32];
  __shared__ __bf16 Bl[128 * 32];
  const int tid = threadIdx.x;
  const int lane = tid & 63;
  const int w = tid >> 6;
  const int wm = w >> 1, wn = w & 1;
  const int n0 = blockIdx.x * 128;
  const int m0 = blockIdx.y * 128;

  const __bf16* Wz = W;
  __bf16* outb = (__bf16*)outp;
  float*  outf = (float*)outp;
  if (MODE == 0) {
    Wz   = W + (size_t)blockIdx.z * (KDIM * KDIM);
    outb = (__bf16*)outp + (size_t)blockIdx.z * ((size_t)BT_ * D_);
  }

  // staging: per wave, 2 chunks of 1024B per matrix; lane supplies 16B
  const int srow = w * 16 + (lane >> 2);
  const int scol = (lane & 3) * 8;
  const __bf16* Ag0 = A  + (size_t)(m0 + srow) * KDIM + scol;
  const __bf16* Ag1 = Ag0 + (size_t)64 * KDIM;
  const __bf16* Bg0 = Wz + (size_t)(n0 + srow) * KDIM + scol;
  const __bf16* Bg1 = Bg0 + (size_t)64 * KDIM;
  __bf16* Al0 = &Al[(w * 16) * 32];        // wave-uniform LDS bases
  __bf16* Al1 = &Al[(64 + w * 16) * 32];
  __bf16* Bl0 = &Bl[(w * 16) * 32];
  __bf16* Bl1 = &Bl[(64 + w * 16) * 32];

  f32x4_t acc[4][4];
#pragma unroll
  for (int i = 0; i < 4; i++)
#pragma unroll
    for (int j = 0; j < 4; j++) acc[i][j] = (f32x4_t){0.f, 0.f, 0.f, 0.f};

  for (int k0 = 0; k0 < KDIM; k0 += 32) {
    __syncthreads();                 // previous tile fully consumed
    gload16(Ag0 + k0, Al0);
    gload16(Ag1 + k0, Al1);
    gload16(Bg0 + k0, Bl0);
    gload16(Bg1 + k0, Bl1);
    __syncthreads();                 // compiler drains vmcnt before barrier

    bf16x8_t af[4], bfr[4];
#pragma unroll
    for (int i = 0; i < 4; i++)
      af[i] = *(const bf16x8_t*)&Al[(wm * 64 + i * 16 + (lane & 15)) * 32 + (lane >> 4) * 8];
#pragma unroll
    for (int j = 0; j < 4; j++)
      bfr[j] = *(const bf16x8_t*)&Bl[(wn * 64 + j * 16 + (lane & 15)) * 32 + (lane >> 4) * 8];
#pragma unroll
    for (int i = 0; i < 4; i++)
#pragma unroll
      for (int j = 0; j < 4; j++)
        acc[i][j] = __builtin_amdgcn_mfma_f32_16x16x32_bf16(af[i], bfr[j], acc[i][j], 0, 0, 0);
  }

  // epilogue: C/D layout col=lane&15, row=(lane>>4)*4+reg  [m89-verified]
  const int rbase = m0 + wm * 64 + ((lane >> 4) << 2);
  const int cbase = n0 + wn * 64 + (lane & 15);
#pragma unroll
  for (int i = 0; i < 4; i++) {
#pragma unroll
    for (int j = 0; j < 4; j++) {
      int cc = cbase + j * 16;
#pragma unroll
      for (int r = 0; r < 4; r++) {
        int m = rbase + i * 16 + r;
        if (MODE == 0) {
          int hh = cc >> 6, dd = cc & 63;
          int bb = m >> 8, tt = m & 255;
          outb[(((size_t)bb * H_ + hh) * T_ + tt) * HD_ + dd] = (__bf16)acc[i][j][r];
        } else {
          outf[(size_t)m * D_ + cc] = acc[i][j][r];
        }
      }
    }
  }
}

// ---------------- in-place RMSNorm + RoPE on Q and K ----------------
// 2 rows per wave (32 lanes/row, 2 elems/lane). rotate_half pairs d <-> d+32
// => lane l2 pairs with l2^16 within its 32-lane group.
__global__ __launch_bounds__(256) void norm_rope(
    __bf16* __restrict__ qb, __bf16* __restrict__ kb,
    const float* __restrict__ gq, const float* __restrict__ gk,
    const float* __restrict__ rc, const float* __restrict__ rs) {
  const int gid = blockIdx.x * 256 + threadIdx.x;
  const int wid = gid >> 6;
  const int lane = gid & 63;
  const int l2 = lane & 31;
  const int half = lane >> 5;
  const int nw = (gridDim.x * 256) >> 6;
  const int NROWS = B_ * H_ * T_;  // 524288 rows per tensor; pairs = 524288 total
  for (int idx = wid; idx < NROWS; idx += nw) {
    int ri = idx * 2 + half;
    int isk = ri >= NROWS;
    int r = isk ? ri - NROWS : ri;
    __bf16* base = isk ? kb : qb;
    const float* g = isk ? gk : gq;
    size_t off = (size_t)r * HD_ + 2 * l2;
    unsigned u = *(const unsigned*)&base[off];
    float v0 = (float)__builtin_bit_cast(__bf16, (unsigned short)(u & 0xffffu));
    float v1 = (float)__builtin_bit_cast(__bf16, (unsigned short)(u >> 16));
    float ss = v0 * v0 + v1 * v1;
#pragma unroll
    for (int m = 1; m < 32; m <<= 1) ss += __shfl_xor(ss, m);
    float rn = rsqrtf(ss * (1.0f / HD_) + 1e-6f);
    v0 *= rn * g[2 * l2];
    v1 *= rn * g[2 * l2 + 1];
    int t = r & (T_ - 1);
    int j0 = (2 * l2) & 31;
    float c0 = rc[t * 32 + j0], c1 = rc[t * 32 + j0 + 1];
    float s0 = rs[t * 32 + j0], s1 = rs[t * 32 + j0 + 1];
    float p0 = __shfl_xor(v0, 16);
    float p1 = __shfl_xor(v1, 16);
    float sg = (l2 < 16) ? -1.f : 1.f;
    float o0 = v0 * c0 + sg * p0 * s0;
    float o1 = v1 * c1 + sg * p1 * s1;
    unsigned short h0 = __builtin_bit_cast(unsigned short, (__bf16)o0);
    unsigned short h1 = __builtin_bit_cast(unsigned short, (__bf16)o1);
    *(unsigned*)&base[off] = (unsigned)h0 | ((unsigned)h1 << 16);
  }
}

// ---------------- attention: one block per (b,h), 8 waves, causal+softcap ----------------
__global__ __launch_bounds__(512, 1) void attn_kernel(
    const __bf16* __restrict__ qb, const __bf16* __restrict__ kb,
    const __bf16* __restrict__ vb, __bf16* __restrict__ ob) {
  __shared__ __bf16 Kl[256][72];      // keys row-major, +8 pad kills 16-way conflicts
  __shared__ __bf16 VT[64][264];      // V transposed (d-major) so B-frag reads are contiguous-K
  __shared__ __bf16 Pl[8][16][264];   // per-wave P staging
  const int bh = blockIdx.x;
  const __bf16* Qg = qb + (size_t)bh * (T_ * HD_);
  const __bf16* Kg = kb + (size_t)bh * (T_ * HD_);
  const __bf16* Vg = vb + (size_t)bh * (T_ * HD_);
  const int tid = threadIdx.x, lane = tid & 63, w = tid >> 6;
  const int bI = bh >> 3, hI = bh & 7;

#pragma unroll
  for (int p = 0; p < 4; p++) {
    int t = p * 64 + (tid >> 3);
    int d0 = (tid & 7) * 8;
    *(bf16x8_t*)&Kl[t][d0] = *(const bf16x8_t*)&Kg[t * HD_ + d0];
    bf16x8_t vv = *(const bf16x8_t*)&Vg[t * HD_ + d0];
#pragma unroll
    for (int j = 0; j < 8; j++) VT[d0 + j][t] = vv[j];
  }
  __syncthreads();

  const int l15 = lane & 15;
  const int lg = lane >> 4;
  const f32x4_t zero = {0.f, 0.f, 0.f, 0.f};
  const float NEGINF = -__builtin_inff();

  for (int it = 0; it < 2; it++) {
    const int q0 = it * 128 + w * 16;           // this wave's 16 q-rows
    bf16x8_t aq0 = *(const bf16x8_t*)&Qg[(q0 + l15) * HD_ + lg * 8];
    bf16x8_t aq1 = *(const bf16x8_t*)&Qg[(q0 + l15) * HD_ + 32 + lg * 8];
    const int ntiles = it * 8 + w + 1;          // causal: key tiles needed
    const int ntiles_e = (ntiles + 1) & ~1;     // even, so PV k-chunks are fully written

    // QK^T
    f32x4_t sc[16];
#pragma unroll
    for (int n = 0; n < 16; n++) {
      if (n < ntiles_e) {
        bf16x8_t kb0 = *(const bf16x8_t*)&Kl[n * 16 + l15][lg * 8];
        bf16x8_t kb1 = *(const bf16x8_t*)&Kl[n * 16 + l15][32 + lg * 8];
        f32x4_t a = __builtin_amdgcn_mfma_f32_16x16x32_bf16(aq0, kb0, zero, 0, 0, 0);
        a = __builtin_amdgcn_mfma_f32_16x16x32_bf16(aq1, kb1, a, 0, 0, 0);
        sc[n] = a;
      }
    }

    // scale + softcap + causal mask + row-max
    const int qr = q0 + (lg << 2);
    f32x4_t mx = {NEGINF, NEGINF, NEGINF, NEGINF};
#pragma unroll
    for (int n = 0; n < 16; n++) {
      if (n < ntiles_e) {
        int key = n * 16 + l15;
#pragma unroll
        for (int r = 0; r < 4; r++) {
          float s = sc[n][r] * 0.125f;          // hd^-0.5
          float e2 = __expf(s * 0.04f);         // e^(2*s/50)
          float cap = 50.f * (e2 - 1.f) / (e2 + 1.f);
          float v = (key <= qr + r) ? cap : NEGINF;
          sc[n][r] = v;
          mx[r] = fmaxf(mx[r], v);
        }
      }
    }
#pragma unroll
    for (int off = 1; off < 16; off <<= 1) {
#pragma unroll
      for (int r = 0; r < 4; r++) mx[r] = fmaxf(mx[r], __shfl_xor(mx[r], off));
    }

    // exp + row-sum + stage P (bf16) to LDS
    f32x4_t ls = {0.f, 0.f, 0.f, 0.f};
#pragma unroll
    for (int n = 0; n < 16; n++) {
      if (n < ntiles_e) {
#pragma unroll
        for (int r = 0; r < 4; r++) {
          float p = __expf(sc[n][r] - mx[r]);   // masked: exp(-inf)=0
          ls[r] += p;
          Pl[w][(lg << 2) + r][n * 16 + l15] = (__bf16)p;
        }
      }
    }
#pragma unroll
    for (int off = 1; off < 16; off <<= 1) {
#pragma unroll
      for (int r = 0; r < 4; r++) ls[r] += __shfl_xor(ls[r], off);
    }

    // wave-private LDS RAW fence (no cross-wave dep => no __syncthreads needed)
    asm volatile("s_waitcnt lgkmcnt(0)" ::: "memory");
    __builtin_amdgcn_sched_barrier(0);

    // PV
    f32x4_t o[4];
#pragma unroll
    for (int j = 0; j < 4; j++) o[j] = zero;
    const int nch = ntiles_e >> 1;
#pragma unroll
    for (int kc = 0; kc < 8; kc++) {
      if (kc < nch) {
        bf16x8_t pa = *(const bf16x8_t*)&Pl[w][l15][kc * 32 + lg * 8];
#pragma unroll
        for (int j = 0; j < 4; j++) {
          bf16x8_t bv = *(const bf16x8_t*)&VT[j * 16 + l15][kc * 32 + lg * 8];
          o[j] = __builtin_amdgcn_mfma_f32_16x16x32_bf16(pa, bv, o[j], 0, 0, 0);
        }
      }
    }

    float rl[4];
#pragma unroll
    for (int r = 0; r < 4; r++) rl[r] = 1.0f / ls[r];
#pragma unroll
    for (int j = 0; j < 4; j++) {
      int dd = j * 16 + l15;
#pragma unroll
      for (int r = 0; r < 4; r++) {
        int q = qr + r;
        ob[((size_t)(bI * T_ + q)) * D_ + hI * HD_ + dd] = (__bf16)(o[j][r] * rl[r]);
      }
    }
  }
}

// ---------------- launch ----------------
extern "C" void kernel_launch(void* const* d_in, const int* in_sizes, int n_in,
                              void* d_out, int out_size, void* d_ws, size_t ws_size,
                              hipStream_t stream) {
  (void)in_sizes; (void)n_in; (void)out_size; (void)ws_size;
  const float* x  = (const float*)d_in[0];
  const float* wq = (const float*)d_in[1];
  const float* wk = (const float*)d_in[2];
  const float* wv = (const float*)d_in[3];
  const float* wo = (const float*)d_in[4];
  const float* gq = (const float*)d_in[5];
  const float* gk = (const float*)d_in[6];

  // ws layout (bytes): xb 64MB (aliased by attn-out) | q 64MB | k 64MB | v 64MB | w 2MB | rope 64KB
  char* ws = (char*)d_ws;
  __bf16* xb   = (__bf16*)ws;
  __bf16* qkvb = (__bf16*)(ws + 67108864UL);
  __bf16* qb = qkvb;
  __bf16* kb = qkvb + 33554432UL;
  __bf16* vb = qkvb + 67108864UL;
  __bf16* wb = (__bf16*)(ws + 4UL * 67108864UL);
  float*  rc = (float*)(ws + 4UL * 67108864UL + 2097152UL);
  float*  rs = rc + 8192;
  __bf16* ob = xb;  // alias: xb dead after QKV GEMM

  cast_weights<<<dim3(256), 256, 0, stream>>>(wq, wk, wv, wo, wb);
  rope_init<<<dim3(32), 256, 0, stream>>>(rc, rs);
  cast_x<<<dim3(2048), 256, 0, stream>>>(x, xb);
  gemm_bt<0><<<dim3(4, 512, 3), 256, 0, stream>>>(xb, wb, (void*)qkvb);
  norm_rope<<<dim3(2048), 256, 0, stream>>>(qb, kb, gq, gk, rc, rs);
  attn_kernel<<<dim3(2048), 512, 0, stream>>>(qb, kb, vb, ob);
  gemm_bt<1><<<dim3(4, 512, 1), 256, 0, stream>>>(ob, wb + 3UL * 262144UL, d_out);
}

// Round 2
// 370.807 us; speedup vs baseline: 1.2900x; 1.2900x over previous
//
#include <hip/hip_runtime.h>
#include <cstdint>
#include <cstddef>

// Problem constants (reference: B=256, T=256, D=512, H=8, hd=64)
#define B_   256
#define T_   256
#define D_   512
#define H_   8
#define HD_  64
#define BT_  65536
#define KDIM 512

typedef __bf16 bf16x8_t __attribute__((ext_vector_type(8)));
typedef __bf16 bf16x4_t __attribute__((ext_vector_type(4)));
typedef float  f32x4_t  __attribute__((ext_vector_type(4)));

__device__ __forceinline__ void gload16(const void* gp, void* lp) {
  // async global->LDS, 16B per lane; LDS dest = wave-uniform base + lane*16
  __builtin_amdgcn_global_load_lds(
      (const __attribute__((address_space(1))) void*)gp,
      (__attribute__((address_space(3))) void*)lp, 16, 0, 0);
}

// ---------------- fused prep: cast x, cast weights, rope tables ----------------
__global__ __launch_bounds__(256) void prep(
    const float* __restrict__ x,
    const float* __restrict__ wq, const float* __restrict__ wk,
    const float* __restrict__ wv, const float* __restrict__ wo,
    __bf16* __restrict__ xb, __bf16* __restrict__ wb,
    float* __restrict__ rc, float* __restrict__ rs) {
  const int b = blockIdx.x;
  if (b < 2048) {
    for (size_t i = (size_t)b * 256 + threadIdx.x; i < 8388608UL; i += 524288UL) {
      f32x4_t v = *(const f32x4_t*)&x[i * 4];
      bf16x4_t o;
      o[0] = (__bf16)v[0]; o[1] = (__bf16)v[1]; o[2] = (__bf16)v[2]; o[3] = (__bf16)v[3];
      *(bf16x4_t*)&xb[i * 4] = o;
    }
  } else if (b < 2304) {
    for (int i = (b - 2048) * 256 + threadIdx.x; i < 262144; i += 65536) {
      int which = i >> 16;
      int off   = (i & 65535) * 4;
      const float* src = (which == 0) ? wq : (which == 1) ? wk : (which == 2) ? wv : wo;
      f32x4_t v = *(const f32x4_t*)&src[off];
      bf16x4_t o;
      o[0] = (__bf16)v[0]; o[1] = (__bf16)v[1]; o[2] = (__bf16)v[2]; o[3] = (__bf16)v[3];
      *(bf16x4_t*)&wb[(size_t)which * 262144 + off] = o;
    }
  } else {
    int idx = (b - 2304) * 256 + threadIdx.x;
    if (idx < T_ * 32) {
      int t = idx >> 5, j = idx & 31;
      float inv = powf(10000.f, -(float)j * (1.0f / 32.0f));  // 10000^(-2j/64)
      float a = (float)t * inv;
      rc[idx] = cosf(a);
      rs[idx] = sinf(a);
    }
  }
}

// ---------------- bt-GEMM: out[m,e] = sum_d A[m,d] * W[e,d] ----------------
// 128x128 tile, BK=32, 4 waves (2x2), m97 structure, XCD-swizzled flat grid.
// MODE 0: fused RMSNorm+RoPE epilogue for z=0/1, bf16 scatter to (B,H,T,hd).
// MODE 1: f32 row-major (m, 512) to d_out.
template <int MODE>
__global__ __launch_bounds__(256) void gemm_bt(
    const __bf16* __restrict__ A, const __bf16* __restrict__ W,
    void* __restrict__ outp,
    const float* __restrict__ gq, const float* __restrict__ gk,
    const float* __restrict__ rc, const float* __restrict__ rs) {
  __shared__ __bf16 Al[128 * 32];
  __shared__ __bf16 Bl[128 * 32];
  const int tid = threadIdx.x;
  const int lane = tid & 63;
  const int w = tid >> 6;
  const int wm = w >> 1, wn = w & 1;

  // XCD-aware swizzle: contiguous tile chunk per XCD (grid % 8 == 0)
  const int cpx = gridDim.x >> 3;
  const int swz = (blockIdx.x & 7) * cpx + (blockIdx.x >> 3);
  const int bx = swz & 3;
  const int by = (swz >> 2) & 511;
  const int bz = swz >> 11;            // 0..2 (MODE 0), always 0 (MODE 1)
  const int n0 = bx * 128;
  const int m0 = by * 128;

  const __bf16* Wz = W;
  __bf16* outb = (__bf16*)outp;
  float*  outf = (float*)outp;
  if (MODE == 0) {
    Wz   = W + (size_t)bz * (KDIM * KDIM);
    outb = (__bf16*)outp + (size_t)bz * ((size_t)BT_ * D_);
  }

  const int srow = w * 16 + (lane >> 2);
  const int scol = (lane & 3) * 8;
  const __bf16* Ag0 = A  + (size_t)(m0 + srow) * KDIM + scol;
  const __bf16* Ag1 = Ag0 + (size_t)64 * KDIM;
  const __bf16* Bg0 = Wz + (size_t)(n0 + srow) * KDIM + scol;
  const __bf16* Bg1 = Bg0 + (size_t)64 * KDIM;
  __bf16* Al0 = &Al[(w * 16) * 32];
  __bf16* Al1 = &Al[(64 + w * 16) * 32];
  __bf16* Bl0 = &Bl[(w * 16) * 32];
  __bf16* Bl1 = &Bl[(64 + w * 16) * 32];

  f32x4_t acc[4][4];
#pragma unroll
  for (int i = 0; i < 4; i++)
#pragma unroll
    for (int j = 0; j < 4; j++) acc[i][j] = (f32x4_t){0.f, 0.f, 0.f, 0.f};

  for (int k0 = 0; k0 < KDIM; k0 += 32) {
    __syncthreads();
    gload16(Ag0 + k0, Al0);
    gload16(Ag1 + k0, Al1);
    gload16(Bg0 + k0, Bl0);
    gload16(Bg1 + k0, Bl1);
    __syncthreads();

    bf16x8_t af[4], bfr[4];
#pragma unroll
    for (int i = 0; i < 4; i++)
      af[i] = *(const bf16x8_t*)&Al[(wm * 64 + i * 16 + (lane & 15)) * 32 + (lane >> 4) * 8];
#pragma unroll
    for (int j = 0; j < 4; j++)
      bfr[j] = *(const bf16x8_t*)&Bl[(wn * 64 + j * 16 + (lane & 15)) * 32 + (lane >> 4) * 8];
#pragma unroll
    for (int i = 0; i < 4; i++)
#pragma unroll
      for (int j = 0; j < 4; j++)
        acc[i][j] = __builtin_amdgcn_mfma_f32_16x16x32_bf16(af[i], bfr[j], acc[i][j], 0, 0, 0);
  }

  // epilogue: C/D layout col=lane&15, row=(lane>>4)*4+reg  [m89-verified]
  const int l15 = lane & 15;
  const int rbase = m0 + wm * 64 + ((lane >> 4) << 2);
  const int cbase = n0 + wn * 64 + l15;

  if (MODE == 1) {
#pragma unroll
    for (int i = 0; i < 4; i++)
#pragma unroll
      for (int j = 0; j < 4; j++) {
        int cc = cbase + j * 16;
#pragma unroll
        for (int r = 0; r < 4; r++)
          outf[(size_t)(rbase + i * 16 + r) * D_ + cc] = acc[i][j][r];
      }
    return;
  }

  const int hh = (n0 + wn * 64) >> 6;  // head index (wave owns exactly one head's cols)
  if (bz == 2) {
    // V: plain bf16 scatter
#pragma unroll
    for (int i = 0; i < 4; i++)
#pragma unroll
      for (int r = 0; r < 4; r++) {
        int m = rbase + i * 16 + r;
        size_t obase = (((size_t)(m >> 8) * H_ + hh) * T_ + (m & 255)) * HD_;
#pragma unroll
        for (int j = 0; j < 4; j++)
          outb[obase + j * 16 + l15] = (__bf16)acc[i][j][r];
      }
  } else {
    // Q/K: RMSNorm (f32, pre-rounding) + RoPE fused
    const float* g = bz ? gk : gq;
    const float gv0 = g[l15], gv1 = g[16 + l15], gv2 = g[32 + l15], gv3 = g[48 + l15];
#pragma unroll
    for (int i = 0; i < 4; i++) {
#pragma unroll
      for (int r = 0; r < 4; r++) {
        float a0 = acc[i][0][r], a1 = acc[i][1][r], a2 = acc[i][2][r], a3 = acc[i][3][r];
        float ss = a0 * a0 + a1 * a1 + a2 * a2 + a3 * a3;
#pragma unroll
        for (int off = 1; off < 16; off <<= 1) ss += __shfl_xor(ss, off);
        float rn = rsqrtf(ss * 0.015625f + 1e-6f);
        float v0 = a0 * rn * gv0, v1 = a1 * rn * gv1;
        float v2 = a2 * rn * gv2, v3 = a3 * rn * gv3;
        int m = rbase + i * 16 + r;
        int t = m & 255;
        float c0 = rc[t * 32 + l15], c1 = rc[t * 32 + 16 + l15];
        float s0 = rs[t * 32 + l15], s1 = rs[t * 32 + 16 + l15];
        float o0 = v0 * c0 - v2 * s0;
        float o1 = v1 * c1 - v3 * s1;
        float o2 = v2 * c0 + v0 * s0;
        float o3 = v3 * c1 + v1 * s1;
        size_t obase = (((size_t)(m >> 8) * H_ + hh) * T_ + (m & 255)) * HD_;
        outb[obase + l15]      = (__bf16)o0;
        outb[obase + 16 + l15] = (__bf16)o1;
        outb[obase + 32 + l15] = (__bf16)o2;
        outb[obase + 48 + l15] = (__bf16)o3;
      }
    }
  }
}

// ---------------- attention: one block per (b,h), 8 balanced waves ----------------
// Fixed-shift softmax (shift = SOFT_CAP = 50): scores are capped at 50 and the
// diagonal guarantees rowmax >= 0, so exp(cap-50) never meaningfully underflows
// (worst lost weight < e^-37 of row max -> FTZ, negligible).
__global__ __launch_bounds__(512, 1) void attn_kernel(
    const __bf16* __restrict__ qb, const __bf16* __restrict__ kb,
    const __bf16* __restrict__ vb, __bf16* __restrict__ ob) {
  __shared__ __bf16 Kl[256][72];      // +8 pad: 2-way banks on frag reads (free)
  __shared__ __bf16 VT[64][264];      // V transposed so PV B-frags are contiguous-K
  __shared__ __bf16 Pl[8][16][264];   // per-wave P staging
  const int bh = blockIdx.x;
  const __bf16* Qg = qb + (size_t)bh * (T_ * HD_);
  const __bf16* Kg = kb + (size_t)bh * (T_ * HD_);
  const __bf16* Vg = vb + (size_t)bh * (T_ * HD_);
  const int tid = threadIdx.x, lane = tid & 63, w = tid >> 6;
  const int bI = bh >> 3, hI = bh & 7;

#pragma unroll
  for (int p = 0; p < 4; p++) {
    int t = p * 64 + (tid >> 3);
    int d0 = (tid & 7) * 8;
    *(bf16x8_t*)&Kl[t][d0] = *(const bf16x8_t*)&Kg[t * HD_ + d0];
    bf16x8_t vv = *(const bf16x8_t*)&Vg[t * HD_ + d0];
#pragma unroll
    for (int j = 0; j < 8; j++) VT[d0 + j][t] = vv[j];
  }
  __syncthreads();

  const int l15 = lane & 15;
  const int lg = lane >> 4;
  const f32x4_t zero = {0.f, 0.f, 0.f, 0.f};
  // raw * 0.125 (hd^-1/2) * 0.04 (2/SOFT_CAP) * log2(e), for e2 = 2^(raw*C1)
  const float C1 = 0.0072134752f;
  const float LOG2E = 1.44269504f;

  for (int half = 0; half < 2; half++) {
    const int qt = half ? (15 - w) : w;      // balanced: every wave 18 even-tiles total
    const int q0 = qt * 16;
    bf16x8_t aq0 = *(const bf16x8_t*)&Qg[(q0 + l15) * HD_ + lg * 8];
    bf16x8_t aq1 = *(const bf16x8_t*)&Qg[(q0 + l15) * HD_ + 32 + lg * 8];
    const int ntiles_e = (qt + 2) & ~1;      // causal tiles, rounded even
    const int qr = q0 + (lg << 2);

    f32x4_t ls = {0.f, 0.f, 0.f, 0.f};
    for (int n = 0; n < ntiles_e; ++n) {
      bf16x8_t kb0 = *(const bf16x8_t*)&Kl[n * 16 + l15][lg * 8];
      bf16x8_t kb1 = *(const bf16x8_t*)&Kl[n * 16 + l15][32 + lg * 8];
      f32x4_t a = __builtin_amdgcn_mfma_f32_16x16x32_bf16(aq0, kb0, zero, 0, 0, 0);
      a = __builtin_amdgcn_mfma_f32_16x16x32_bf16(aq1, kb1, a, 0, 0, 0);
      const int key = n * 16 + l15;
#pragma unroll
      for (int r = 0; r < 4; r++) {
        float e2 = __builtin_amdgcn_exp2f(a[r] * C1);
        float cm = -100.f * __builtin_amdgcn_rcpf(e2 + 1.f);  // cap - 50
        float p = __builtin_amdgcn_exp2f(cm * LOG2E);
        p = (key <= qr + r) ? p : 0.f;
        ls[r] += p;
        Pl[w][(lg << 2) + r][key] = (__bf16)p;
      }
    }
#pragma unroll
    for (int off = 1; off < 16; off <<= 1) {
#pragma unroll
      for (int r = 0; r < 4; r++) ls[r] += __shfl_xor(ls[r], off);
    }

    // wave-private LDS RAW fence (no cross-wave dep => no __syncthreads)
    asm volatile("s_waitcnt lgkmcnt(0)" ::: "memory");
    __builtin_amdgcn_sched_barrier(0);

    f32x4_t o[4];
#pragma unroll
    for (int j = 0; j < 4; j++) o[j] = zero;
    const int nch = ntiles_e >> 1;
    for (int kc = 0; kc < nch; ++kc) {
      bf16x8_t pa = *(const bf16x8_t*)&Pl[w][l15][kc * 32 + lg * 8];
#pragma unroll
      for (int j = 0; j < 4; j++) {
        bf16x8_t bv = *(const bf16x8_t*)&VT[j * 16 + l15][kc * 32 + lg * 8];
        o[j] = __builtin_amdgcn_mfma_f32_16x16x32_bf16(pa, bv, o[j], 0, 0, 0);
      }
    }

    float rl[4];
#pragma unroll
    for (int r = 0; r < 4; r++) rl[r] = 1.0f / ls[r];
#pragma unroll
    for (int j = 0; j < 4; j++) {
      int dd = j * 16 + l15;
#pragma unroll
      for (int r = 0; r < 4; r++) {
        int q = qr + r;
        ob[((size_t)(bI * T_ + q)) * D_ + hI * HD_ + dd] = (__bf16)(o[j][r] * rl[r]);
      }
    }
  }
}

// ---------------- launch ----------------
extern "C" void kernel_launch(void* const* d_in, const int* in_sizes, int n_in,
                              void* d_out, int out_size, void* d_ws, size_t ws_size,
                              hipStream_t stream) {
  (void)in_sizes; (void)n_in; (void)out_size; (void)ws_size;
  const float* x  = (const float*)d_in[0];
  const float* wq = (const float*)d_in[1];
  const float* wk = (const float*)d_in[2];
  const float* wv = (const float*)d_in[3];
  const float* wo = (const float*)d_in[4];
  const float* gq = (const float*)d_in[5];
  const float* gk = (const float*)d_in[6];

  // ws layout (bytes): xb 64MB (aliased by attn-out) | q 64MB | k 64MB | v 64MB | w 2MB | rope 64KB
  char* ws = (char*)d_ws;
  __bf16* xb   = (__bf16*)ws;
  __bf16* qkvb = (__bf16*)(ws + 67108864UL);
  __bf16* qb = qkvb;
  __bf16* kb = qkvb + 33554432UL;
  __bf16* vb = qkvb + 67108864UL;
  __bf16* wb = (__bf16*)(ws + 4UL * 67108864UL);
  float*  rc = (float*)(ws + 4UL * 67108864UL + 2097152UL);
  float*  rs = rc + 8192;
  __bf16* ob = xb;  // alias: xb dead after QKV GEMM

  prep<<<dim3(2336), 256, 0, stream>>>(x, wq, wk, wv, wo, xb, wb, rc, rs);
  gemm_bt<0><<<dim3(6144), 256, 0, stream>>>(xb, wb, (void*)qkvb, gq, gk, rc, rs);
  attn_kernel<<<dim3(2048), 512, 0, stream>>>(qb, kb, vb, ob);
  gemm_bt<1><<<dim3(2048), 256, 0, stream>>>(ob, wb + 3UL * 262144UL, d_out, nullptr, nullptr, nullptr, nullptr);
}